// Round 1
// baseline (153.426 us; speedup 1.0000x reference)
//
#include <hip/hip_runtime.h>

// YOLO layer: input [B, A*(5+C), H, W] fp32 -> (boxes [B,N,1,4], confs [B,N,C]) fp32
// B=64, A=3, C=80, H=W=76, N=A*H*W=17328
// d_out = boxes flat (B*N*4) then confs flat (B*N*C)

#define Bn 64
#define An 3
#define Cn 80
#define Hn 76
#define Wn 76
#define HW (Hn * Wn)            // 5776
#define Nn (An * HW)            // 17328
#define CHn (5 + Cn)            // 85
#define PAD 77                  // LDS row pitch: 77 % 32 = 13, gcd(13,32)=1 -> conflict-free
#define BOX_TOTAL (Bn * Nn * 4) // 4435968 floats

__device__ __forceinline__ float sigmoidf_(float x) {
    return 1.0f / (1.0f + __expf(-x));
}

__launch_bounds__(256)
__global__ void yolo_kernel(const float* __restrict__ in, float* __restrict__ out) {
    __shared__ float s_in[CHn * PAD];
    __shared__ float s_det[Wn];

    const int bid = blockIdx.x;          // b*A*H + a*H + y
    const int y   = bid % Hn;
    const int t   = bid / Hn;
    const int a   = t % An;
    const int b   = t / An;

    // anchors (block-uniform select, no scratch array)
    const float aw = (a == 0) ? 1.5f : ((a == 1) ? 2.375f : 5.0f);
    const float ah = (a == 0) ? 2.0f : ((a == 1) ? 4.5f   : 3.5f);

    const int tid = threadIdx.x;
    const float* __restrict__ src =
        in + ((size_t)(b * (An * CHn) + a * CHn)) * HW + (size_t)y * Wn;

    // ---- phase 1: stage 85 channels x 76 floats -> LDS (float4 coalesced) ----
    // 85 * 19 = 1615 float4 loads; offsets all multiples of 4 floats -> 16B aligned
    for (int i = tid; i < CHn * 19; i += 256) {
        const int ch = i / 19;
        const int q  = i % 19;
        const float4 v = *(const float4*)(src + (size_t)ch * HW + q * 4);
        float* d = &s_in[ch * PAD + q * 4];
        d[0] = v.x; d[1] = v.y; d[2] = v.z; d[3] = v.w;
    }
    __syncthreads();

    const int n_base = a * HW + y * Wn;

    // ---- phase 2: boxes + det (76 lanes) ----
    if (tid < Wn) {
        const int x = tid;
        const float sx  = sigmoidf_(s_in[0 * PAD + x]);
        const float sy  = sigmoidf_(s_in[1 * PAD + x]);
        const float ew  = __expf(s_in[2 * PAD + x]);
        const float eh  = __expf(s_in[3 * PAD + x]);
        const float det = sigmoidf_(s_in[4 * PAD + x]);
        s_det[x] = det;

        const float bx = (sx + (float)x) * (1.0f / Wn);
        const float by = (sy + (float)y) * (1.0f / Hn);
        const float bw = ew * aw * (1.0f / Wn);
        const float bh = eh * ah * (1.0f / Hn);
        const float bx1 = bx - 0.5f * bw;
        const float by1 = by - 0.5f * bh;

        const size_t n = (size_t)b * Nn + n_base + x;
        float4 box;
        box.x = bx1; box.y = by1; box.z = bx1 + bw; box.w = by1 + bh;
        *(float4*)(out + n * 4) = box;   // 16B-aligned, coalesced across lanes
    }
    __syncthreads();

    // ---- phase 3: confs, c-fastest -> coalesced global stores ----
    // conf[b, n_base+s, c] flat = base + s*80 + c = base + i
    float* __restrict__ confs = out + BOX_TOTAL + ((size_t)b * Nn + n_base) * Cn;
    for (int i = tid; i < Wn * Cn; i += 256) {
        const int s = i / Cn;
        const int c = i % Cn;
        // LDS read: addr = (5+c)*77 + s, lane stride 77 -> conflict-free
        confs[i] = sigmoidf_(s_in[(5 + c) * PAD + s]) * s_det[s];
    }
}

extern "C" void kernel_launch(void* const* d_in, const int* in_sizes, int n_in,
                              void* d_out, int out_size, void* d_ws, size_t ws_size,
                              hipStream_t stream) {
    (void)in_sizes; (void)n_in; (void)d_ws; (void)ws_size; (void)out_size;
    const float* in = (const float*)d_in[0];
    float* out = (float*)d_out;
    const int grid = Bn * An * Hn;  // 14592 blocks
    yolo_kernel<<<grid, 256, 0, stream>>>(in, out);
}

// Round 3
// 142.934 us; speedup vs baseline: 1.0734x; 1.0734x over previous
//
#include <hip/hip_runtime.h>

// YOLO layer: input [B, A*(5+C), H, W] fp32 -> (boxes [B,N,1,4], confs [B,N,C]) fp32
// B=64, A=3, C=80, H=W=76, N=A*H*W=17328
// d_out = boxes flat (B*N*4) then confs flat (B*N*C)

#define Bn 64
#define An 3
#define Cn 80
#define Hn 76
#define Wn 76
#define HW (Hn * Wn)            // 5776
#define Nn (An * HW)            // 17328
#define CHn (5 + Cn)            // 85
#define PAD 77                  // LDS row pitch: 77 % 32 = 13, gcd(13,32)=1 -> conflict-free
#define BOX_TOTAL (Bn * Nn * 4) // 4435968 floats
#define NWG (Bn * An * Hn)      // 14592 = 8 * 1824
#define CPX (NWG / 8)           // 1824 blocks per XCD chunk

typedef float floatx4 __attribute__((ext_vector_type(4)));  // nontemporal-store compatible

__device__ __forceinline__ float sigmoidf_(float x) {
    return 1.0f / (1.0f + __expf(-x));
}

__launch_bounds__(256)
__global__ void yolo_kernel(const float* __restrict__ in, float* __restrict__ out) {
    __shared__ float s_in[CHn * PAD];
    __shared__ float s_det[Wn];

    // XCD-aware swizzle: HW round-robins dispatch index across 8 XCDs;
    // remap so each XCD gets a CONTIGUOUS (b,a,y) chunk -> y-adjacent rows
    // share an L2, recovering the 64B-line overlap between 304B rows.
    const int raw = blockIdx.x;
    const int bid = (raw & 7) * CPX + (raw >> 3);   // bijective: 14592 % 8 == 0

    const int y   = bid % Hn;
    const int t   = bid / Hn;
    const int a   = t % An;
    const int b   = t / An;

    // anchors (block-uniform select)
    const float aw = (a == 0) ? 1.5f : ((a == 1) ? 2.375f : 5.0f);
    const float ah = (a == 0) ? 2.0f : ((a == 1) ? 4.5f   : 3.5f);

    const int tid = threadIdx.x;
    const float* __restrict__ src =
        in + ((size_t)(b * (An * CHn) + a * CHn)) * HW + (size_t)y * Wn;

    // ---- phase 1: stage 85 channels x 76 floats -> LDS (float4 coalesced) ----
    for (int i = tid; i < CHn * 19; i += 256) {
        const int ch = i / 19;
        const int q  = i % 19;
        const float4 v = *(const float4*)(src + (size_t)ch * HW + q * 4);
        float* d = &s_in[ch * PAD + q * 4];
        d[0] = v.x; d[1] = v.y; d[2] = v.z; d[3] = v.w;
    }
    __syncthreads();

    const int n_base = a * HW + y * Wn;

    // ---- phase 2: boxes + det (76 lanes) ----
    if (tid < Wn) {
        const int x = tid;
        const float sx  = sigmoidf_(s_in[0 * PAD + x]);
        const float sy  = sigmoidf_(s_in[1 * PAD + x]);
        const float ew  = __expf(s_in[2 * PAD + x]);
        const float eh  = __expf(s_in[3 * PAD + x]);
        const float det = sigmoidf_(s_in[4 * PAD + x]);
        s_det[x] = det;

        const float bx = (sx + (float)x) * (1.0f / Wn);
        const float by = (sy + (float)y) * (1.0f / Hn);
        const float bw = ew * aw * (1.0f / Wn);
        const float bh = eh * ah * (1.0f / Hn);
        const float bx1 = bx - 0.5f * bw;
        const float by1 = by - 0.5f * bh;

        const size_t n = (size_t)b * Nn + n_base + x;
        floatx4 box;
        box.x = bx1; box.y = by1; box.z = bx1 + bw; box.w = by1 + bh;
        __builtin_nontemporal_store(box, (floatx4*)(out + n * 4)); // streamed, never re-read
    }
    __syncthreads();

    // ---- phase 3: confs, c-fastest -> coalesced nontemporal stores ----
    float* __restrict__ confs = out + BOX_TOTAL + ((size_t)b * Nn + n_base) * Cn;
    for (int i = tid; i < Wn * Cn; i += 256) {
        const int s = i / Cn;
        const int c = i % Cn;
        const float v = sigmoidf_(s_in[(5 + c) * PAD + s]) * s_det[s];
        __builtin_nontemporal_store(v, confs + i);
    }
}

extern "C" void kernel_launch(void* const* d_in, const int* in_sizes, int n_in,
                              void* d_out, int out_size, void* d_ws, size_t ws_size,
                              hipStream_t stream) {
    (void)in_sizes; (void)n_in; (void)d_ws; (void)ws_size; (void)out_size;
    const float* in = (const float*)d_in[0];
    float* out = (float*)d_out;
    yolo_kernel<<<NWG, 256, 0, stream>>>(in, out);
}